// Round 3
// baseline (1175.651 us; speedup 1.0000x reference)
//
#include <hip/hip_runtime.h>
#include <hip/hip_bf16.h>
#include <stdint.h>
#include <stddef.h>

// Problem dims (fixed by reference)
#define HID   2048
#define INTER 8192
#define MOE_I 1024
#define TOK   8192   // B*S = 4*2048

using bf16 = __hip_bfloat16;
typedef __attribute__((ext_vector_type(8))) short short8;   // 8 bf16 = 4 VGPRs
typedef __attribute__((ext_vector_type(4))) float f32x4;

// ---------------------------------------------------------------------------
// async global -> LDS, 16B per lane (global_load_lds_dwordx4). LDS dest is
// wave-uniform base + lane*16; per-lane pointers with lane-stride 16 match.
// ---------------------------------------------------------------------------
__device__ __forceinline__ void gload_lds16(const bf16* g, bf16* l) {
    __builtin_amdgcn_global_load_lds(
        (const __attribute__((address_space(1))) void*)g,
        (__attribute__((address_space(3))) void*)l,
        16, 0, 0);
}

// 8x fp32 -> 8x bf16 packed (16 B)
__device__ __forceinline__ short8 cvt8(float4 a, float4 b) {
    union { short8 s; bf16 h[8]; } u;
    u.h[0] = __float2bfloat16(a.x); u.h[1] = __float2bfloat16(a.y);
    u.h[2] = __float2bfloat16(a.z); u.h[3] = __float2bfloat16(a.w);
    u.h[4] = __float2bfloat16(b.x); u.h[5] = __float2bfloat16(b.y);
    u.h[6] = __float2bfloat16(b.z); u.h[7] = __float2bfloat16(b.w);
    return u.s;
}

__global__ void cast_f32_to_bf16(const float* __restrict__ in,
                                 bf16* __restrict__ out, int n4) {
    int stride = gridDim.x * blockDim.x;
    for (int i = blockIdx.x * blockDim.x + threadIdx.x; i < n4; i += stride) {
        float4 v = reinterpret_cast<const float4*>(in)[i];
        union { uint64_t u; bf16 h[4]; } o;
        o.h[0] = __float2bfloat16(v.x); o.h[1] = __float2bfloat16(v.y);
        o.h[2] = __float2bfloat16(v.z); o.h[3] = __float2bfloat16(v.w);
        reinterpret_cast<uint64_t*>(out)[i] = o.u;
    }
}

// ===========================================================================
// m201-class GEMMs: 2-barrier-per-phase, ring-2 LDS (128 KB), BK=64,
// per-wave 128-row output (MFMA:ds_read = 2.67:1), counted-latency staging
// (all 8 stage loads at phase 0; vmcnt(0) ~3 phases later -> drain hidden).
//
// LDS rows are 64 bf16 = 128 B. Swizzle: 16-B octet o at row r stored at
// o ^ (r&7); staging pre-swizzles the per-lane GLOBAL source column
// (global_load_lds writes linearly); ds_read applies the same XOR.
// Verified round 2: SQ_LDS_BANK_CONFLICT == 0.
//
// Ring-2 safety: stage into slot nxt at phase 0 of iter s is ordered after
// iter s-1's boundary barrier; all reads of nxt finished before each wave's
// s-1 lgkmcnt(0) which precedes that barrier. Reads of cur are covered by
// vmcnt(0) (own loads) + boundary barrier (collective).
// ===========================================================================

// ---------------------------------------------------------------------------
// gemm9_gu: H = swish(X@Wg^T) * (X@Wu^T), bf16. X[M,K], Wg/Wu[N,K] bf16.
// BM=256 x BN=128, 8 waves (2M x 4N), per-wave 128x32 dual-stream.
// Slot = A(256x64) + G(128x64) + U(128x64) = 64 KB; 2 slots = 128 KB.
// ---------------------------------------------------------------------------
__global__ __launch_bounds__(512, 2) void gemm9_gu(
    const bf16* __restrict__ X, const bf16* __restrict__ Wg,
    const bf16* __restrict__ Wu, bf16* __restrict__ H,
    int M, int N, int K)
{
    constexpr int SLOT = 32768;                     // elements per slot (64 KB)
    __shared__ __align__(16) bf16 lds[2 * SLOT];    // 128 KB

    const int tid  = threadIdx.x;
    const int lane = tid & 63;
    const int wave = tid >> 6;
    const int n0 = blockIdx.x * 128;
    const int m0 = blockIdx.y * 256;

    // staging lane map: row = tid>>3 (0..63 within chunk), octet = tid&7,
    // pre-swizzled global col = ((tid&7) ^ (row&7)) * 8 elements
    const int srow = tid >> 3;
    const int scol = (((tid & 7) ^ (srow & 7)) << 3);
    const bf16* pA = X  + (size_t)(m0 + srow) * K + scol;
    const bf16* pG = Wg + (size_t)(n0 + srow) * K + scol;
    const bf16* pU = Wu + (size_t)(n0 + srow) * K + scol;
    const size_t rsk = (size_t)64 * K;              // +64 global rows
    bf16* dl = lds + tid * 8;

    // compute-side
    const int wm = (wave >> 2) * 128;   // 0,128
    const int wn = (wave & 3) * 32;     // 0,32,64,96
    const int r16 = lane & 15;
    const int kq  = lane >> 4;          // 0..3
    const int cswz0 = ((kq       ^ (lane & 7)) << 4);   // ks=0 byte col
    const int cswz1 = (((4 + kq) ^ (lane & 7)) << 4);   // ks=1 byte col
    const char* lb = (const char*)lds;

    int roffA[8], roffW[2];
#pragma unroll
    for (int i = 0; i < 8; i++) roffA[i] = (wm + 16 * i + r16) * 128;
#pragma unroll
    for (int j = 0; j < 2; j++) roffW[j] = (wn + 16 * j + r16) * 128;

    f32x4 accg[8][2] = {};
    f32x4 accu[8][2] = {};
    const int NS = K >> 6;

    // prologue: stage sub-tile 0 -> slot 0 (8 loads)
    {
        bf16* d = dl;
#pragma unroll
        for (int c = 0; c < 4; c++) gload_lds16(pA + c * rsk, d + c * 4096);
        gload_lds16(pG,       d + 16384);
        gload_lds16(pG + rsk, d + 20480);
        gload_lds16(pU,       d + 24576);
        gload_lds16(pU + rsk, d + 28672);
    }
    asm volatile("s_waitcnt vmcnt(0)" ::: "memory");
    __builtin_amdgcn_s_barrier();
    __builtin_amdgcn_sched_barrier(0);

    for (int s = 0; s < NS; s++) {
        const int cur = s & 1;
        const char* cb = lb + (size_t)cur * 65536;
        bf16* d = dl + (cur ^ 1) * SLOT;
        const size_t ko = (size_t)((s + 1 < NS) ? s + 1 : NS - 1) * 64;
        const bf16* qa = pA + ko;
        const bf16* qg = pG + ko;
        const bf16* qu = pU + ko;

        short8 a[4], g[2], u[2];

        // ---- phase 0: stage(s+1, 8 loads) + A[0..3]@ks0 + G/U@ks0, 16 MFMA
#pragma unroll
        for (int c = 0; c < 4; c++) gload_lds16(qa + c * rsk, d + c * 4096);
        gload_lds16(qg,       d + 16384);
        gload_lds16(qg + rsk, d + 20480);
        gload_lds16(qu,       d + 24576);
        gload_lds16(qu + rsk, d + 28672);
#pragma unroll
        for (int ii = 0; ii < 4; ii++)
            a[ii] = *(const short8*)(cb + roffA[ii] + cswz0);
#pragma unroll
        for (int j = 0; j < 2; j++) {
            g[j] = *(const short8*)(cb + 32768 + roffW[j] + cswz0);
            u[j] = *(const short8*)(cb + 49152 + roffW[j] + cswz0);
        }
        __builtin_amdgcn_s_barrier();
        asm volatile("s_waitcnt lgkmcnt(0)" ::: "memory");
        __builtin_amdgcn_sched_barrier(0);
        __builtin_amdgcn_s_setprio(1);
#pragma unroll
        for (int ii = 0; ii < 4; ii++)
#pragma unroll
            for (int j = 0; j < 2; j++) {
                accg[ii][j] = __builtin_amdgcn_mfma_f32_16x16x32_bf16(a[ii], g[j], accg[ii][j], 0, 0, 0);
                accu[ii][j] = __builtin_amdgcn_mfma_f32_16x16x32_bf16(a[ii], u[j], accu[ii][j], 0, 0, 0);
            }
        __builtin_amdgcn_s_setprio(0);
        __builtin_amdgcn_s_barrier();

        // ---- phase 1: A[4..7]@ks0, 16 MFMA (g/u persist)
#pragma unroll
        for (int ii = 0; ii < 4; ii++)
            a[ii] = *(const short8*)(cb + roffA[4 + ii] + cswz0);
        __builtin_amdgcn_s_barrier();
        asm volatile("s_waitcnt lgkmcnt(0)" ::: "memory");
        __builtin_amdgcn_sched_barrier(0);
        __builtin_amdgcn_s_setprio(1);
#pragma unroll
        for (int ii = 0; ii < 4; ii++)
#pragma unroll
            for (int j = 0; j < 2; j++) {
                accg[4 + ii][j] = __builtin_amdgcn_mfma_f32_16x16x32_bf16(a[ii], g[j], accg[4 + ii][j], 0, 0, 0);
                accu[4 + ii][j] = __builtin_amdgcn_mfma_f32_16x16x32_bf16(a[ii], u[j], accu[4 + ii][j], 0, 0, 0);
            }
        __builtin_amdgcn_s_setprio(0);
        __builtin_amdgcn_s_barrier();

        // ---- phase 2: A[0..3]@ks1 + G/U@ks1, 16 MFMA
#pragma unroll
        for (int ii = 0; ii < 4; ii++)
            a[ii] = *(const short8*)(cb + roffA[ii] + cswz1);
#pragma unroll
        for (int j = 0; j < 2; j++) {
            g[j] = *(const short8*)(cb + 32768 + roffW[j] + cswz1);
            u[j] = *(const short8*)(cb + 49152 + roffW[j] + cswz1);
        }
        __builtin_amdgcn_s_barrier();
        asm volatile("s_waitcnt lgkmcnt(0)" ::: "memory");
        __builtin_amdgcn_sched_barrier(0);
        __builtin_amdgcn_s_setprio(1);
#pragma unroll
        for (int ii = 0; ii < 4; ii++)
#pragma unroll
            for (int j = 0; j < 2; j++) {
                accg[ii][j] = __builtin_amdgcn_mfma_f32_16x16x32_bf16(a[ii], g[j], accg[ii][j], 0, 0, 0);
                accu[ii][j] = __builtin_amdgcn_mfma_f32_16x16x32_bf16(a[ii], u[j], accu[ii][j], 0, 0, 0);
            }
        __builtin_amdgcn_s_setprio(0);
        __builtin_amdgcn_s_barrier();

        // ---- phase 3: A[4..7]@ks1, 16 MFMA; boundary: vmcnt(0)+barrier
#pragma unroll
        for (int ii = 0; ii < 4; ii++)
            a[ii] = *(const short8*)(cb + roffA[4 + ii] + cswz1);
        __builtin_amdgcn_s_barrier();
        asm volatile("s_waitcnt lgkmcnt(0)" ::: "memory");
        __builtin_amdgcn_sched_barrier(0);
        __builtin_amdgcn_s_setprio(1);
#pragma unroll
        for (int ii = 0; ii < 4; ii++)
#pragma unroll
            for (int j = 0; j < 2; j++) {
                accg[4 + ii][j] = __builtin_amdgcn_mfma_f32_16x16x32_bf16(a[ii], g[j], accg[4 + ii][j], 0, 0, 0);
                accu[4 + ii][j] = __builtin_amdgcn_mfma_f32_16x16x32_bf16(a[ii], u[j], accu[4 + ii][j], 0, 0, 0);
            }
        __builtin_amdgcn_s_setprio(0);
        asm volatile("s_waitcnt vmcnt(0)" ::: "memory");   // next slot staged (hidden: issued ~3 phases ago)
        __builtin_amdgcn_s_barrier();
        __builtin_amdgcn_sched_barrier(0);
    }

    // epilogue: h = g*sigmoid(g)*u. C/D: col=lane&15, row=(lane>>4)*4+r
#pragma unroll
    for (int i = 0; i < 8; i++) {
        const int rowb = m0 + wm + 16 * i + (lane >> 4) * 4;
#pragma unroll
        for (int j = 0; j < 2; j++) {
            const int col = n0 + wn + 16 * j + r16;
#pragma unroll
            for (int r = 0; r < 4; r++) {
                float g = accg[i][j][r];
                float u = accu[i][j][r];
                float h = g * u / (1.0f + __expf(-g));
                H[(size_t)(rowb + r) * N + col] = __float2bfloat16(h);
            }
        }
    }
}

// ---------------------------------------------------------------------------
// gemm9_down: OUT (+)= Ha @ Bs[:, col0:+Ka]^T (+ Hb @ Br^T if Kb>0), f32.
// BM=256 x BN=256, 8 waves (2M x 4N), per-wave 128x64 (exact m201 geometry).
// Slot = A(256x64) + B(256x64) = 64 KB; 2 slots = 128 KB.
// ---------------------------------------------------------------------------
__global__ __launch_bounds__(512, 2) void gemm9_down(
    const bf16* __restrict__ Ha, const bf16* __restrict__ Bs,
    long ldBs, long col0,
    const bf16* __restrict__ Hb, const bf16* __restrict__ Br,
    long ldBr, float* __restrict__ OUT,
    int M, int N, int Ka, int Kb, int acc)
{
    constexpr int SLOT = 32768;
    __shared__ __align__(16) bf16 lds[2 * SLOT];

    const int tid  = threadIdx.x;
    const int lane = tid & 63;
    const int wave = tid >> 6;
    const int n0 = blockIdx.x * 256;
    const int m0 = blockIdx.y * 256;

    const int srow = tid >> 3;
    const int scol = (((tid & 7) ^ (srow & 7)) << 3);
    const bf16* pA1 = Ha + (size_t)(m0 + srow) * Ka + scol;
    const bf16* pB1 = Bs + (size_t)(n0 + srow) * ldBs + col0 + scol;
    const bf16* pA2 = Hb + (size_t)(m0 + srow) * Kb + scol;
    const bf16* pB2 = Br + (size_t)(n0 + srow) * ldBr + scol;
    const size_t rA1 = (size_t)64 * Ka, rB1 = (size_t)64 * ldBs;
    const size_t rA2 = (size_t)64 * Kb, rB2 = (size_t)64 * ldBr;
    bf16* dl = lds + tid * 8;

    const int wm = (wave >> 2) * 128;   // 0,128
    const int wn = (wave & 3) * 64;     // 0,64,128,192
    const int r16 = lane & 15;
    const int kq  = lane >> 4;
    const int cswz0 = ((kq       ^ (lane & 7)) << 4);
    const int cswz1 = (((4 + kq) ^ (lane & 7)) << 4);
    const char* lb = (const char*)lds;

    int roffA[8], roffB[4];
#pragma unroll
    for (int i = 0; i < 8; i++) roffA[i] = (wm + 16 * i + r16) * 128;
#pragma unroll
    for (int j = 0; j < 4; j++) roffB[j] = (wn + 16 * j + r16) * 128;

    f32x4 acc4[8][4] = {};
    const int NS1 = Ka >> 6;
    const int NS  = NS1 + (Kb >> 6);

    // prologue: stage sub-tile 0 (segment 1) -> slot 0 (8 loads)
    {
        bf16* d = dl;
#pragma unroll
        for (int c = 0; c < 4; c++) gload_lds16(pA1 + c * rA1, d + c * 4096);
#pragma unroll
        for (int c = 0; c < 4; c++) gload_lds16(pB1 + c * rB1, d + 16384 + c * 4096);
    }
    asm volatile("s_waitcnt vmcnt(0)" ::: "memory");
    __builtin_amdgcn_s_barrier();
    __builtin_amdgcn_sched_barrier(0);

    for (int s = 0; s < NS; s++) {
        const int cur = s & 1;
        const char* cb = lb + (size_t)cur * 65536;
        bf16* d = dl + (cur ^ 1) * SLOT;
        const int sp = (s + 1 < NS) ? s + 1 : NS - 1;
        const bf16 *qa, *qb; size_t ra, rb;
        if (sp < NS1) {
            size_t ko = (size_t)sp * 64;
            qa = pA1 + ko; qb = pB1 + ko; ra = rA1; rb = rB1;
        } else {
            size_t ko = (size_t)(sp - NS1) * 64;
            qa = pA2 + ko; qb = pB2 + ko; ra = rA2; rb = rB2;
        }

        short8 a[4], b[4];

        // ---- phase 0: stage(s+1) + A[0..3]@ks0 + B@ks0, 16 MFMA
#pragma unroll
        for (int c = 0; c < 4; c++) gload_lds16(qa + c * ra, d + c * 4096);
#pragma unroll
        for (int c = 0; c < 4; c++) gload_lds16(qb + c * rb, d + 16384 + c * 4096);
#pragma unroll
        for (int ii = 0; ii < 4; ii++)
            a[ii] = *(const short8*)(cb + roffA[ii] + cswz0);
#pragma unroll
        for (int j = 0; j < 4; j++)
            b[j] = *(const short8*)(cb + 32768 + roffB[j] + cswz0);
        __builtin_amdgcn_s_barrier();
        asm volatile("s_waitcnt lgkmcnt(0)" ::: "memory");
        __builtin_amdgcn_sched_barrier(0);
        __builtin_amdgcn_s_setprio(1);
#pragma unroll
        for (int ii = 0; ii < 4; ii++)
#pragma unroll
            for (int j = 0; j < 4; j++)
                acc4[ii][j] = __builtin_amdgcn_mfma_f32_16x16x32_bf16(a[ii], b[j], acc4[ii][j], 0, 0, 0);
        __builtin_amdgcn_s_setprio(0);
        __builtin_amdgcn_s_barrier();

        // ---- phase 1: A[4..7]@ks0, 16 MFMA (b persists)
#pragma unroll
        for (int ii = 0; ii < 4; ii++)
            a[ii] = *(const short8*)(cb + roffA[4 + ii] + cswz0);
        __builtin_amdgcn_s_barrier();
        asm volatile("s_waitcnt lgkmcnt(0)" ::: "memory");
        __builtin_amdgcn_sched_barrier(0);
        __builtin_amdgcn_s_setprio(1);
#pragma unroll
        for (int ii = 0; ii < 4; ii++)
#pragma unroll
            for (int j = 0; j < 4; j++)
                acc4[4 + ii][j] = __builtin_amdgcn_mfma_f32_16x16x32_bf16(a[ii], b[j], acc4[4 + ii][j], 0, 0, 0);
        __builtin_amdgcn_s_setprio(0);
        __builtin_amdgcn_s_barrier();

        // ---- phase 2: A[0..3]@ks1 + B@ks1, 16 MFMA
#pragma unroll
        for (int ii = 0; ii < 4; ii++)
            a[ii] = *(const short8*)(cb + roffA[ii] + cswz1);
#pragma unroll
        for (int j = 0; j < 4; j++)
            b[j] = *(const short8*)(cb + 32768 + roffB[j] + cswz1);
        __builtin_amdgcn_s_barrier();
        asm volatile("s_waitcnt lgkmcnt(0)" ::: "memory");
        __builtin_amdgcn_sched_barrier(0);
        __builtin_amdgcn_s_setprio(1);
#pragma unroll
        for (int ii = 0; ii < 4; ii++)
#pragma unroll
            for (int j = 0; j < 4; j++)
                acc4[ii][j] = __builtin_amdgcn_mfma_f32_16x16x32_bf16(a[ii], b[j], acc4[ii][j], 0, 0, 0);
        __builtin_amdgcn_s_setprio(0);
        __builtin_amdgcn_s_barrier();

        // ---- phase 3: A[4..7]@ks1, 16 MFMA; boundary: vmcnt(0)+barrier
#pragma unroll
        for (int ii = 0; ii < 4; ii++)
            a[ii] = *(const short8*)(cb + roffA[4 + ii] + cswz1);
        __builtin_amdgcn_s_barrier();
        asm volatile("s_waitcnt lgkmcnt(0)" ::: "memory");
        __builtin_amdgcn_sched_barrier(0);
        __builtin_amdgcn_s_setprio(1);
#pragma unroll
        for (int ii = 0; ii < 4; ii++)
#pragma unroll
            for (int j = 0; j < 4; j++)
                acc4[4 + ii][j] = __builtin_amdgcn_mfma_f32_16x16x32_bf16(a[ii], b[j], acc4[4 + ii][j], 0, 0, 0);
        __builtin_amdgcn_s_setprio(0);
        asm volatile("s_waitcnt vmcnt(0)" ::: "memory");
        __builtin_amdgcn_s_barrier();
        __builtin_amdgcn_sched_barrier(0);
    }

#pragma unroll
    for (int i = 0; i < 8; i++) {
        const int rowb = m0 + wm + 16 * i + (lane >> 4) * 4;
#pragma unroll
        for (int j = 0; j < 4; j++) {
            const int col = n0 + wn + 16 * j + r16;
#pragma unroll
            for (int r = 0; r < 4; r++) {
                const size_t idx = (size_t)(rowb + r) * N + col;
                float v = acc4[i][j][r];
                OUT[idx] = acc ? (OUT[idx] + v) : v;
            }
        }
    }
}

// ===========================================================================
// Round-1 kernels kept as fallbacks (proven correct) for degraded ws cases.
// ===========================================================================
__global__ __launch_bounds__(256) void gemm_gu_bb(
    const bf16* __restrict__ X, const bf16* __restrict__ Wg,
    const bf16* __restrict__ Wu, bf16* __restrict__ H,
    int M, int N, int K)
{
    __shared__ bf16 sA[128 * 32];
    __shared__ bf16 sG[64 * 32];
    __shared__ bf16 sU[64 * 32];

    const int tid  = threadIdx.x;
    const int lane = tid & 63;
    const int wave = tid >> 6;
    const int n0 = blockIdx.x * 64;
    const int m0 = blockIdx.y * 128;

    const int srow = tid >> 2;
    const int scol = (tid & 3) * 8;
    const bf16* ga = X  + (size_t)(m0 + srow) * K + scol;
    const bf16* gg = Wg + (size_t)(n0 + srow) * K + scol;
    const bf16* gu = Wu + (size_t)(n0 + srow) * K + scol;
    const size_t rowskip = (size_t)64 * K;
    bf16* la = sA + tid * 8;
    bf16* lg = sG + tid * 8;
    bf16* lu = sU + tid * 8;

    const int wm  = (wave >> 1) * 64;
    const int wn  = (wave & 1) * 32;
    const int r16 = lane & 15;
    const int kq8 = (lane >> 4) * 8;

    f32x4 accg[4][2] = {};
    f32x4 accu[4][2] = {};

    for (int k0 = 0; k0 < K; k0 += 32) {
        gload_lds16(ga,           la);
        gload_lds16(ga + rowskip, la + 2048);
        gload_lds16(gg,           lg);
        gload_lds16(gu,           lu);
        ga += 32; gg += 32; gu += 32;
        __syncthreads();

        short8 af[4], bg[2], bu[2];
#pragma unroll
        for (int i = 0; i < 4; i++)
            af[i] = *reinterpret_cast<const short8*>(sA + (wm + 16 * i + r16) * 32 + kq8);
#pragma unroll
        for (int j = 0; j < 2; j++) {
            bg[j] = *reinterpret_cast<const short8*>(sG + (wn + 16 * j + r16) * 32 + kq8);
            bu[j] = *reinterpret_cast<const short8*>(sU + (wn + 16 * j + r16) * 32 + kq8);
        }
#pragma unroll
        for (int i = 0; i < 4; i++)
#pragma unroll
            for (int j = 0; j < 2; j++) {
                accg[i][j] = __builtin_amdgcn_mfma_f32_16x16x32_bf16(af[i], bg[j], accg[i][j], 0, 0, 0);
                accu[i][j] = __builtin_amdgcn_mfma_f32_16x16x32_bf16(af[i], bu[j], accu[i][j], 0, 0, 0);
            }
        __syncthreads();
    }

#pragma unroll
    for (int i = 0; i < 4; i++) {
        const int rowb = m0 + wm + 16 * i + (lane >> 4) * 4;
#pragma unroll
        for (int j = 0; j < 2; j++) {
            const int col = n0 + wn + 16 * j + r16;
#pragma unroll
            for (int r = 0; r < 4; r++) {
                float g = accg[i][j][r];
                float u = accu[i][j][r];
                float h = g * u / (1.0f + __expf(-g));
                H[(size_t)(rowb + r) * N + col] = __float2bfloat16(h);
            }
        }
    }
}

__global__ __launch_bounds__(256) void gemm_gu_f32(
    const float* __restrict__ X, const float* __restrict__ Wg,
    const float* __restrict__ Wu, bf16* __restrict__ H,
    int M, int N, int K)
{
    __shared__ bf16 sA[128 * 32];
    __shared__ bf16 sG[64 * 32];
    __shared__ bf16 sU[64 * 32];

    const int tid  = threadIdx.x;
    const int lane = tid & 63;
    const int wave = tid >> 6;
    const int n0 = blockIdx.x * 64;
    const int m0 = blockIdx.y * 128;

    const int srow = tid >> 2;
    const int scol = (tid & 3) * 8;

    const int wm  = (wave >> 1) * 64;
    const int wn  = (wave & 1) * 32;
    const int r16 = lane & 15;
    const int kq8 = (lane >> 4) * 8;

    f32x4 accg[4][2] = {};
    f32x4 accu[4][2] = {};

    for (int k0 = 0; k0 < K; k0 += 32) {
#pragma unroll
        for (int seg = 0; seg < 2; seg++) {
            const int row = srow + 64 * seg;
            const float* pa = X + (size_t)(m0 + row) * K + k0 + scol;
            float4 a0 = *(const float4*)pa, a1 = *(const float4*)(pa + 4);
            *(short8*)(sA + row * 32 + scol) = cvt8(a0, a1);
        }
        {
            const float* pg = Wg + (size_t)(n0 + srow) * K + k0 + scol;
            const float* pu = Wu + (size_t)(n0 + srow) * K + k0 + scol;
            float4 g0 = *(const float4*)pg, g1 = *(const float4*)(pg + 4);
            float4 u0 = *(const float4*)pu, u1 = *(const float4*)(pu + 4);
            *(short8*)(sG + srow * 32 + scol) = cvt8(g0, g1);
            *(short8*)(sU + srow * 32 + scol) = cvt8(u0, u1);
        }
        __syncthreads();

        short8 af[4], bg[2], bu[2];
#pragma unroll
        for (int i = 0; i < 4; i++)
            af[i] = *reinterpret_cast<const short8*>(sA + (wm + 16 * i + r16) * 32 + kq8);
#pragma unroll
        for (int j = 0; j < 2; j++) {
            bg[j] = *reinterpret_cast<const short8*>(sG + (wn + 16 * j + r16) * 32 + kq8);
            bu[j] = *reinterpret_cast<const short8*>(sU + (wn + 16 * j + r16) * 32 + kq8);
        }
#pragma unroll
        for (int i = 0; i < 4; i++)
#pragma unroll
            for (int j = 0; j < 2; j++) {
                accg[i][j] = __builtin_amdgcn_mfma_f32_16x16x32_bf16(af[i], bg[j], accg[i][j], 0, 0, 0);
                accu[i][j] = __builtin_amdgcn_mfma_f32_16x16x32_bf16(af[i], bu[j], accu[i][j], 0, 0, 0);
            }
        __syncthreads();
    }

#pragma unroll
    for (int i = 0; i < 4; i++) {
        const int rowb = m0 + wm + 16 * i + (lane >> 4) * 4;
#pragma unroll
        for (int j = 0; j < 2; j++) {
            const int col = n0 + wn + 16 * j + r16;
#pragma unroll
            for (int r = 0; r < 4; r++) {
                float g = accg[i][j][r];
                float u = accu[i][j][r];
                float h = g * u / (1.0f + __expf(-g));
                H[(size_t)(rowb + r) * N + col] = __float2bfloat16(h);
            }
        }
    }
}

__global__ __launch_bounds__(256) void gemm_down2(
    const bf16* __restrict__ Ha, const bf16* __restrict__ Bs16,
    const float* __restrict__ Bs32, int sflag, long ldBs, long col0,
    const bf16* __restrict__ Hb, const bf16* __restrict__ Br16,
    const float* __restrict__ Br32, int rflag, long ldBr,
    float* __restrict__ OUT, int M, int N, int Ka, int Kb, int acc)
{
    __shared__ bf16 sA[128 * 32];
    __shared__ bf16 sB[128 * 32];

    const int tid  = threadIdx.x;
    const int lane = tid & 63;
    const int wave = tid >> 6;
    const int n0 = blockIdx.x * 128;
    const int m0 = blockIdx.y * 128;

    const int srow = tid >> 2;
    const int scol = (tid & 3) * 8;
    bf16* la = sA + tid * 8;
    bf16* lb = sB + tid * 8;

    const int wm  = (wave >> 1) * 64;
    const int wn  = (wave & 1) * 64;
    const int r16 = lane & 15;
    const int kq8 = (lane >> 4) * 8;

    f32x4 acc4[4][4] = {};

    {
        const bf16* ga = Ha + (size_t)(m0 + srow) * Ka + scol;
        const size_t rska = (size_t)64 * Ka;
        const bf16* gb = Bs16 + (size_t)(n0 + srow) * ldBs + col0 + scol;
        const size_t rskb = (size_t)64 * ldBs;
        for (int k0 = 0; k0 < Ka; k0 += 32) {
            gload_lds16(ga,        la);
            gload_lds16(ga + rska, la + 2048);
            ga += 32;
            if (sflag) {
                gload_lds16(gb,        lb);
                gload_lds16(gb + rskb, lb + 2048);
                gb += 32;
            } else {
#pragma unroll
                for (int seg = 0; seg < 2; seg++) {
                    const int row = srow + 64 * seg;
                    const float* pb = Bs32 + (size_t)(n0 + row) * ldBs + col0 + k0 + scol;
                    float4 b0 = *(const float4*)pb, b1 = *(const float4*)(pb + 4);
                    *(short8*)(sB + row * 32 + scol) = cvt8(b0, b1);
                }
            }
            __syncthreads();

            short8 af[4], bw[4];
#pragma unroll
            for (int i = 0; i < 4; i++)
                af[i] = *reinterpret_cast<const short8*>(sA + (wm + 16 * i + r16) * 32 + kq8);
#pragma unroll
            for (int j = 0; j < 4; j++)
                bw[j] = *reinterpret_cast<const short8*>(sB + (wn + 16 * j + r16) * 32 + kq8);
#pragma unroll
            for (int i = 0; i < 4; i++)
#pragma unroll
                for (int j = 0; j < 4; j++)
                    acc4[i][j] = __builtin_amdgcn_mfma_f32_16x16x32_bf16(af[i], bw[j], acc4[i][j], 0, 0, 0);
            __syncthreads();
        }
    }
    if (Kb > 0) {
        const bf16* ga = Hb + (size_t)(m0 + srow) * Kb + scol;
        const size_t rska = (size_t)64 * Kb;
        const bf16* gb = Br16 + (size_t)(n0 + srow) * ldBr + scol;
        const size_t rskb = (size_t)64 * ldBr;
        for (int k0 = 0; k0 < Kb; k0 += 32) {
            gload_lds16(ga,        la);
            gload_lds16(ga + rska, la + 2048);
            ga += 32;
            if (rflag) {
                gload_lds16(gb,        lb);
                gload_lds16(gb + rskb, lb + 2048);
                gb += 32;
            } else {
#pragma unroll
                for (int seg = 0; seg < 2; seg++) {
                    const int row = srow + 64 * seg;
                    const float* pb = Br32 + (size_t)(n0 + row) * ldBr + k0 + scol;
                    float4 b0 = *(const float4*)pb, b1 = *(const float4*)(pb + 4);
                    *(short8*)(sB + row * 32 + scol) = cvt8(b0, b1);
                }
            }
            __syncthreads();

            short8 af[4], bw[4];
#pragma unroll
            for (int i = 0; i < 4; i++)
                af[i] = *reinterpret_cast<const short8*>(sA + (wm + 16 * i + r16) * 32 + kq8);
#pragma unroll
            for (int j = 0; j < 4; j++)
                bw[j] = *reinterpret_cast<const short8*>(sB + (wn + 16 * j + r16) * 32 + kq8);
#pragma unroll
            for (int i = 0; i < 4; i++)
#pragma unroll
                for (int j = 0; j < 4; j++)
                    acc4[i][j] = __builtin_amdgcn_mfma_f32_16x16x32_bf16(af[i], bw[j], acc4[i][j], 0, 0, 0);
            __syncthreads();
        }
    }

#pragma unroll
    for (int i = 0; i < 4; i++) {
        const int rowb = m0 + wm + 16 * i + (lane >> 4) * 4;
#pragma unroll
        for (int j = 0; j < 4; j++) {
            const int col = n0 + wn + 16 * j + r16;
#pragma unroll
            for (int r = 0; r < 4; r++) {
                const size_t idx = (size_t)(rowb + r) * N + col;
                float v = acc4[i][j][r];
                OUT[idx] = acc ? (OUT[idx] + v) : v;
            }
        }
    }
}

// ---------------------------------------------------------------------------
// launch: greedy ws allocation. Primary path (all bf16 buffers) uses the
// m201-class kernels; otherwise fall back to round-1 logic.
// ---------------------------------------------------------------------------
extern "C" void kernel_launch(void* const* d_in, const int* in_sizes, int n_in,
                              void* d_out, int out_size, void* d_ws, size_t ws_size,
                              hipStream_t stream) {
    const float* x       = (const float*)d_in[0];
    // d_in[1] = router_weight: dead (topk_idx < 8 always => comb_w == 1)
    const float* sh_gate = (const float*)d_in[2];
    const float* sh_up   = (const float*)d_in[3];
    const float* sh_down = (const float*)d_in[4];
    const float* r_gate  = (const float*)d_in[5];
    const float* r_up    = (const float*)d_in[6];
    const float* r_down  = (const float*)d_in[7];
    float* out = (float*)d_out;

    auto cast = [&](const float* in, bf16* o, size_t n) {
        int n4 = (int)(n / 4);
        int blocks = (n4 + 255) / 256;
        if (blocks > 2048) blocks = 2048;
        cast_f32_to_bf16<<<dim3(blocks), dim3(256), 0, stream>>>(in, o, n4);
    };

    const size_t HS_MIN = (size_t)TOK * 128 * 2;
    size_t limit = (ws_size > HS_MIN) ? ws_size - HS_MIN : 0;
    size_t off = 0;
    auto take = [&](size_t bytes) -> bf16* {
        if (off + bytes <= limit) { bf16* p = (bf16*)((char*)d_ws + off); off += bytes; return p; }
        return nullptr;
    };

    bf16* Xb = take((size_t)TOK   * HID * 2);
    bf16* Gs = take((size_t)INTER * HID * 2);
    bf16* Us = take((size_t)INTER * HID * 2);
    bf16* Hr = take((size_t)TOK   * MOE_I * 2);

    if (Xb && Gs && Us && Hr) {
        bf16* Ds = take((size_t)INTER * HID * 2);
        bf16* Gr = take((size_t)MOE_I * HID * 2);
        bf16* Ur = take((size_t)MOE_I * HID * 2);
        bf16* Dr = take((size_t)MOE_I * HID * 2);

        size_t remain = ws_size - off;
        int Nc = 128;
        const int cands[7] = {8192, 4096, 2048, 1024, 512, 256, 128};
        for (int i = 0; i < 7; i++)
            if ((size_t)TOK * cands[i] * 2 <= remain) { Nc = cands[i]; break; }
        bf16* Hs = (bf16*)((char*)d_ws + off);

        cast(x,       Xb, (size_t)TOK   * HID);
        cast(sh_gate, Gs, (size_t)INTER * HID);
        cast(sh_up,   Us, (size_t)INTER * HID);
        if (Ds) cast(sh_down, Ds, (size_t)INTER * HID);
        if (Gr) cast(r_gate,  Gr, (size_t)MOE_I * HID);
        if (Ur) cast(r_up,    Ur, (size_t)MOE_I * HID);
        if (Dr) cast(r_down,  Dr, (size_t)MOE_I * HID);

        if (Ds && Gr && Ur && Dr) {
            // ---- primary: m201-class deep-pipelined path ----
            gemm9_gu<<<dim3(MOE_I / 128, TOK / 256), dim3(512), 0, stream>>>(
                Xb, Gr, Ur, Hr, TOK, MOE_I, HID);
            const int nch = INTER / Nc;
            for (int c = 0; c < nch; c++) {
                gemm9_gu<<<dim3(Nc / 128, TOK / 256), dim3(512), 0, stream>>>(
                    Xb, Gs + (size_t)c * Nc * HID, Us + (size_t)c * Nc * HID,
                    Hs, TOK, Nc, HID);
                gemm9_down<<<dim3(HID / 256, TOK / 256), dim3(512), 0, stream>>>(
                    Hs, Ds, (long)INTER, (long)c * Nc,
                    Hr, Dr, (long)MOE_I,
                    out, TOK, HID, Nc, (c == 0) ? MOE_I : 0, (c == 0) ? 0 : 1);
            }
            return;
        }

        // ---- round-1 mixed path ----
        if (Gr && Ur)
            gemm_gu_bb<<<dim3(MOE_I / 64, TOK / 128), dim3(256), 0, stream>>>(
                Xb, Gr, Ur, Hr, TOK, MOE_I, HID);
        else
            gemm_gu_f32<<<dim3(MOE_I / 64, TOK / 128), dim3(256), 0, stream>>>(
                x, r_gate, r_up, Hr, TOK, MOE_I, HID);

        const int nch = INTER / Nc;
        for (int c = 0; c < nch; c++) {
            gemm_gu_bb<<<dim3(Nc / 64, TOK / 128), dim3(256), 0, stream>>>(
                Xb, Gs + (size_t)c * Nc * HID, Us + (size_t)c * Nc * HID,
                Hs, TOK, Nc, HID);
            gemm_down2<<<dim3(HID / 128, TOK / 128), dim3(256), 0, stream>>>(
                Hs, Ds, sh_down, Ds ? 1 : 0, (long)INTER, (long)c * Nc,
                Hr, Dr, r_down, Dr ? 1 : 0, (long)MOE_I,
                out, TOK, HID, Nc, (c == 0) ? MOE_I : 0, (c == 0) ? 0 : 1);
        }
        return;
    }

    // ---- full fallback: fp32 fused-cast everywhere ----
    {
        const size_t hrBytes = (size_t)TOK * MOE_I * 2;
        int Nc = 128;
        const int cands[6] = {8192, 4096, 2048, 1024, 512, 256};
        for (int i = 0; i < 6; i++)
            if ((size_t)TOK * cands[i] * 2 + hrBytes <= ws_size) { Nc = cands[i]; break; }
        bf16* Hs = (bf16*)d_ws;
        bf16* Hr2 = Hs + (size_t)TOK * Nc;

        gemm_gu_f32<<<dim3(MOE_I / 64, TOK / 128), dim3(256), 0, stream>>>(
            x, r_gate, r_up, Hr2, TOK, MOE_I, HID);
        const int nch = INTER / Nc;
        for (int c = 0; c < nch; c++) {
            gemm_gu_f32<<<dim3(Nc / 64, TOK / 128), dim3(256), 0, stream>>>(
                x, sh_gate + (size_t)c * Nc * HID, sh_up + (size_t)c * Nc * HID,
                Hs, TOK, Nc, HID);
            gemm_down2<<<dim3(HID / 128, TOK / 128), dim3(256), 0, stream>>>(
                Hs, nullptr, sh_down, 0, (long)INTER, (long)c * Nc,
                Hr2, nullptr, r_down, 0, (long)MOE_I,
                out, TOK, HID, Nc, (c == 0) ? MOE_I : 0, (c == 0) ? 0 : 1);
        }
    }
}